// Round 11
// baseline (144.571 us; speedup 1.0000x reference)
//
#include <hip/hip_runtime.h>
#include <hip/hip_bf16.h>
#include <stdint.h>

typedef unsigned short u16;
using bf16x8 = __attribute__((ext_vector_type(8))) short;
using f32x4v = __attribute__((ext_vector_type(4))) float;

#define BATCH 4
#define CDIM 512
#define NQ 1024
#define NKV 2048
#define NH 8
#define HD 64

__device__ __forceinline__ u16 f2bf(float f) {
  uint32_t u = __float_as_uint(f);
  u += 0x7fffu + ((u >> 16) & 1u);
  return (u16)(u >> 16);
}
// compiler-path bf16 cast (pairs fuse to v_cvt_pk_bf16_f32)
__device__ __forceinline__ u16 f2bf_c(float f) {
  __hip_bfloat16 h = __float2bfloat16(f);
  union { __hip_bfloat16 b; u16 u; } cv;
  cv.b = h;
  return cv.u;
}

// ---------------- fp32 -> bf16 convert (weights) ----------------
__global__ void cvt_w(const float* __restrict__ in, u16* __restrict__ out, int n) {
  int i = blockIdx.x * 256 + threadIdx.x;
  if (i < n) out[i] = f2bf(in[i]);
}

// ---------------- (B, C, N) f32 -> (B, N, C) bf16 ----------------
__global__ void pack_cvt(const float* __restrict__ in, u16* __restrict__ out,
                         int C, int N) {
  __shared__ float t[32][33];
  int b = blockIdx.z;
  int n0 = blockIdx.x * 32, c0 = blockIdx.y * 32;
  int tx = threadIdx.x, ty = threadIdx.y;
  const float* ib = in + (size_t)b * C * N;
#pragma unroll
  for (int i = 0; i < 4; ++i)
    t[ty + i * 8][tx] = ib[(size_t)(c0 + ty + i * 8) * N + n0 + tx];
  __syncthreads();
  u16* ob = out + (size_t)b * N * C;
#pragma unroll
  for (int i = 0; i < 4; ++i)
    ob[(size_t)(n0 + ty + i * 8) * C + c0 + tx] = f2bf(t[tx][ty + i * 8]);
}

// ---------------- V slice of khv -> vt[b,h,d,kv] ----------------
__global__ void transpose_vh(const u16* __restrict__ khv, u16* __restrict__ vt) {
  __shared__ u16 t[32][33];
  int bh = blockIdx.z;
  int b = bh >> 3, h = bh & 7;
  int kv0 = blockIdx.x * 32, d0 = blockIdx.y * 32;
  int tx = threadIdx.x, ty = threadIdx.y;
  const u16* ib = khv + (size_t)b * NKV * 1024 + 512 + h * HD;
#pragma unroll
  for (int i = 0; i < 4; ++i)
    t[ty + i * 8][tx] = ib[(size_t)(kv0 + ty + i * 8) * 1024 + d0 + tx];
  __syncthreads();
  u16* ob = vt + (size_t)bh * HD * NKV;
#pragma unroll
  for (int i = 0; i < 4; ++i)
    ob[(size_t)(d0 + ty + i * 8) * NKV + kv0 + tx] = t[tx][ty + i * 8];
}

// ---------------- GEMM: C[m,n] = sum_k A[m,k]*B[n,k] + bias[n] ----------------
// OUTMODE 0: bf16 row-major (ldc). OUTMODE 2: f32 transposed to (B, C, NQ).
template <int OUTMODE>
__global__ __launch_bounds__(256) void gemm_bt(
    const u16* __restrict__ A, const u16* __restrict__ B,
    const float* __restrict__ bias, void* __restrict__ Cout,
    int M, int N, int K, int ldc) {
  __shared__ alignas(16) u16 lsA[2][128 * 32];
  __shared__ alignas(16) u16 lsB[2][128 * 32];
  int t = threadIdx.x, l = t & 63, w = t >> 6;
  int lr = l & 15, lg = l >> 4;
  int wr = w >> 1, wc = w & 1;
  int m0 = blockIdx.x * 128, n0 = blockIdx.y * 128;
  const u16* Ag = A + (size_t)m0 * K;
  const u16* Bg = B + (size_t)n0 * K;
  f32x4v acc[4][4] = {};

  auto stage = [&](int buf, int k0) {
#pragma unroll
    for (int r = 0; r < 2; ++r) {
      int e = (r * 256 + t) * 8;
      int row = e >> 5, col = e & 31;
      __builtin_amdgcn_global_load_lds(
          (const __attribute__((address_space(1))) void*)(Ag + (size_t)row * K + k0 + col),
          (__attribute__((address_space(3))) void*)(&lsA[buf][r * 2048 + w * 512]),
          16, 0, 0);
      __builtin_amdgcn_global_load_lds(
          (const __attribute__((address_space(1))) void*)(Bg + (size_t)row * K + k0 + col),
          (__attribute__((address_space(3))) void*)(&lsB[buf][r * 2048 + w * 512]),
          16, 0, 0);
    }
  };

  stage(0, 0);
  int nk = K >> 5, cur = 0;
  for (int kt = 0; kt < nk; ++kt) {
    __syncthreads();
    if (kt + 1 < nk) stage(cur ^ 1, (kt + 1) << 5);
    const u16* la = lsA[cur];
    const u16* lb = lsB[cur];
    bf16x8 af[4], bfr[4];
#pragma unroll
    for (int m = 0; m < 4; ++m)
      af[m] = *(const bf16x8*)&la[(wr * 64 + m * 16 + lr) * 32 + lg * 8];
#pragma unroll
    for (int n = 0; n < 4; ++n)
      bfr[n] = *(const bf16x8*)&lb[(wc * 64 + n * 16 + lr) * 32 + lg * 8];
#pragma unroll
    for (int m = 0; m < 4; ++m)
#pragma unroll
      for (int n = 0; n < 4; ++n)
        acc[m][n] = __builtin_amdgcn_mfma_f32_16x16x32_bf16(af[m], bfr[n], acc[m][n], 0, 0, 0);
    cur ^= 1;
  }

  // epilogue: C/D layout col=lane&15, row=(lane>>4)*4+j
#pragma unroll
  for (int m = 0; m < 4; ++m) {
    int row = m0 + wr * 64 + m * 16 + lg * 4;
#pragma unroll
    for (int n = 0; n < 4; ++n) {
      int col = n0 + wc * 64 + n * 16 + lr;
      float bv = bias[col];
      if (OUTMODE == 0) {
#pragma unroll
        for (int j = 0; j < 4; ++j)
          ((u16*)Cout)[(size_t)(row + j) * ldc + col] = f2bf(acc[m][n][j] + bv);
      } else {
        // transposed store: token rows row..row+3 -> out[b][col][tok]
        int bb = row >> 10, tok = row & 1023;
        f32x4v v;
#pragma unroll
        for (int j = 0; j < 4; ++j) v[j] = acc[m][n][j] + bv;
        *(f32x4v*)&((float*)Cout)[((size_t)bb * CDIM + col) * NQ + tok] = v;
      }
    }
  }
}

// ---------------- flash attention v6: K staged, V direct from L2 ----------
// grid (32 bh, 16 qtiles), block 256 = 4 waves, 16 q-rows/wave, KVBLK=64.
// LDS-pipe was the bottleneck (18 b128 reads/tile/wave ~= measured kernel
// cycles). V is L2-resident (256KB/head, 16 same-head blocks/XCD) -> read V
// fragments directly from global vt, dropping 8 of 18 LDS b128 reads + all
// V staging. K stays triple-buffered with counted vmcnt (2 loads/wave/tile).
__global__ __launch_bounds__(256) void attn_fwd(
    const u16* __restrict__ qh,   // (B*NQ, 512)
    const u16* __restrict__ khv,  // (B*NKV, 1024): cols 0..511 = K
    const u16* __restrict__ vt,   // (B*8*64, NKV)
    u16* __restrict__ ao) {       // (B*NQ, 512)
  __shared__ alignas(16) u16 lsK[3][64 * 64];
  __shared__ alignas(16) u16 plds[4][16 * 64];
  const float scale2 = 0.125f * 1.44269504089f;  // scale * log2(e)
  int t = threadIdx.x, l = t & 63, w = t >> 6;
  int lr = l & 15, lg = l >> 4;
  int bh = blockIdx.x, b = bh >> 3, h = bh & 7;
  int q0 = blockIdx.y * 64 + w * 16;
  const u16* Qb = qh + ((size_t)b * NQ + q0) * 512 + h * HD;
  const u16* Kb = khv + (size_t)b * NKV * 1024 + h * HD;
  const u16* Vtb = vt + (size_t)bh * HD * NKV;

  int srow = w * 8 + (l >> 3);   // 0..31: tile row this lane stages
  int c16 = l & 7;               // 16B-block index within 128B row

  auto stageK = [&](int buf, int kv0) {
#pragma unroll
    for (int i = 0; i < 2; ++i) {
      int row = srow + i * 32;
      int sc = c16 ^ (row & 7);  // inverse-swizzled source block
      __builtin_amdgcn_global_load_lds(
          (const __attribute__((address_space(1))) void*)(Kb + (size_t)(kv0 + row) * 1024 + sc * 8),
          (__attribute__((address_space(3))) void*)(&lsK[buf][w * 512 + i * 2048]),
          16, 0, 0);
    }
  };

  bf16x8 qa[2];
#pragma unroll
  for (int s = 0; s < 2; ++s)
    qa[s] = *(const bf16x8*)(Qb + (size_t)lr * 512 + s * 32 + lg * 8);

  float m2 = -INFINITY;     // running max (log2 domain) for q row = q0+lr
  float lrow = 0.f;         // running denom
  f32x4v od[4] = {};        // O^T: od[n][j] -> d = n*16+lg*4+j, q = lr

  char* pwave = (char*)&plds[w][0];
  int swz = (lr & 7) << 4;

  stageK(0, 0);
  stageK(1, 64);
  const int NT = NKV / 64;
  for (int kt = 0; kt < NT; ++kt) {
    // t's 2 K-loads done; t+1's 2 stay in flight (last iter: drain)
    if (kt < NT - 1) {
      asm volatile("s_waitcnt vmcnt(2)" ::: "memory");
    } else {
      asm volatile("s_waitcnt vmcnt(0)" ::: "memory");
    }
    __builtin_amdgcn_s_barrier();
    __builtin_amdgcn_sched_barrier(0);
    if (kt + 2 < NT) stageK((kt + 2) % 3, (kt + 2) * 64);
    const u16* lk = lsK[kt % 3];

    // V fragments direct from global (L2-resident); independent of softmax,
    // issued early so ~200cy L2 latency hides under QK^T + softmax.
    bf16x8 vfr[2][4];
#pragma unroll
    for (int sk = 0; sk < 2; ++sk)
#pragma unroll
      for (int n = 0; n < 4; ++n)
        vfr[sk][n] = *(const bf16x8*)(Vtb + (size_t)(n * 16 + lr) * NKV + kt * 64 + sk * 32 + lg * 8);

    // S^T = K Q^T: A = K-frag, B = Q-frag
    f32x4v sfr[4] = {};
    __builtin_amdgcn_s_setprio(1);
#pragma unroll
    for (int sk = 0; sk < 2; ++sk)
#pragma unroll
      for (int n = 0; n < 4; ++n) {
        bf16x8 kb = *(const bf16x8*)&lk[(n * 16 + lr) * 64 + ((sk * 4 + lg) ^ (lr & 7)) * 8];
        sfr[n] = __builtin_amdgcn_mfma_f32_16x16x32_bf16(kb, qa[sk], sfr[n], 0, 0, 0);
      }
    __builtin_amdgcn_s_setprio(0);

    // lane-local max over 16 kv values (log2 domain)
    float pm = fmaxf(fmaxf(fmaxf(sfr[0][0], sfr[0][1]), fmaxf(sfr[0][2], sfr[0][3])),
                     fmaxf(fmaxf(sfr[1][0], sfr[1][1]), fmaxf(sfr[1][2], sfr[1][3])));
    float pm2 = fmaxf(fmaxf(fmaxf(sfr[2][0], sfr[2][1]), fmaxf(sfr[2][2], sfr[2][3])),
                      fmaxf(fmaxf(sfr[3][0], sfr[3][1]), fmaxf(sfr[3][2], sfr[3][3])));
    pm = fmaxf(pm, pm2) * scale2;
    pm = fmaxf(pm, __shfl_xor(pm, 16, 64));
    pm = fmaxf(pm, __shfl_xor(pm, 32, 64));

    // exact-skip rescale
    if (__any(pm > m2)) {
      float mn = fmaxf(m2, pm);
      float alpha = __builtin_amdgcn_exp2f(m2 - mn);
      m2 = mn;
      lrow *= alpha;
#pragma unroll
      for (int n = 0; n < 4; ++n)
#pragma unroll
        for (int j = 0; j < 4; ++j)
          od[n][j] *= alpha;
    }

    float p[4][4];
    float rs = 0.f;
#pragma unroll
    for (int n = 0; n < 4; ++n)
#pragma unroll
      for (int j = 0; j < 4; ++j) {
        float e = __builtin_amdgcn_exp2f(fmaf(sfr[n][j], scale2, -m2));
        p[n][j] = e;
        rs += e;
      }
    rs += __shfl_xor(rs, 16, 64);
    rs += __shfl_xor(rs, 32, 64);
    lrow += rs;

    // P[q=lr][kv] -> LDS, 4x ds_write_b64, swizzled (cvt_pk pairs)
#pragma unroll
    for (int n = 0; n < 4; ++n) {
      ushort4 pw;
      pw.x = f2bf_c(p[n][0]); pw.y = f2bf_c(p[n][1]);
      pw.z = f2bf_c(p[n][2]); pw.w = f2bf_c(p[n][3]);
      *(ushort4*)(pwave + lr * 128 + ((n * 32 + lg * 8) ^ swz)) = pw;
    }

    // O^T += V^T P^T: A = V^T-frag (registers), B = P^T from plds
    __builtin_amdgcn_s_setprio(1);
#pragma unroll
    for (int sk = 0; sk < 2; ++sk) {
      bf16x8 pa = *(const bf16x8*)(pwave + lr * 128 + ((sk * 64 + lg * 16) ^ swz));
#pragma unroll
      for (int n = 0; n < 4; ++n)
        od[n] = __builtin_amdgcn_mfma_f32_16x16x32_bf16(vfr[sk][n], pa, od[n], 0, 0, 0);
    }
    __builtin_amdgcn_s_setprio(0);
  }

  float rl = 1.0f / lrow;
  u16* aob = ao + ((size_t)b * NQ + q0 + lr) * 512 + h * HD + lg * 4;
#pragma unroll
  for (int n = 0; n < 4; ++n) {
    ushort4 o;
    o.x = f2bf_c(od[n][0] * rl); o.y = f2bf_c(od[n][1] * rl);
    o.z = f2bf_c(od[n][2] * rl); o.w = f2bf_c(od[n][3] * rl);
    *(ushort4*)(aob + n * 16) = o;
  }
}

// ---------------- launch ----------------
extern "C" void kernel_launch(void* const* d_in, const int* in_sizes, int n_in,
                              void* d_out, int out_size, void* d_ws, size_t ws_size,
                              hipStream_t stream) {
  const float* q    = (const float*)d_in[0];
  const float* kv   = (const float*)d_in[1];
  const float* Wqkv = (const float*)d_in[2];
  const float* bqkv = (const float*)d_in[3];
  const float* Wout = (const float*)d_in[4];
  const float* bout = (const float*)d_in[5];
  float* out = (float*)d_out;
  uint8_t* ws = (uint8_t*)d_ws;

  u16* qf  = (u16*)(ws + 0);            // 4 MB  (B*NQ, 512) bf16
  u16* kvf = (u16*)(ws + (4u << 20));   // 8 MB  (B*NKV, 512) bf16
  u16* wq  = (u16*)(ws + (12u << 20));  // 1.5MB Wqkv bf16 (1536,512)
  u16* wo  = (u16*)(ws + (14u << 20));  // 0.5MB Wout bf16 (512,512)
  u16* qhb = (u16*)(ws + (15u << 20));  // 4 MB  (B*NQ, 512)
  u16* khv = (u16*)(ws + (19u << 20));  // 16 MB (B*NKV, 1024) K|V
  u16* vt  = (u16*)(ws + (35u << 20));  // 8 MB  (B*8*64, NKV)
  u16* ao  = (u16*)(ws + (43u << 20));  // 4 MB  (B*NQ, 512)

  dim3 blk256(256), blkT(32, 8);

  cvt_w<<<dim3((1536 * 512 + 255) / 256), blk256, 0, stream>>>(Wqkv, wq, 1536 * 512);
  cvt_w<<<dim3((512 * 512 + 255) / 256), blk256, 0, stream>>>(Wout, wo, 512 * 512);
  pack_cvt<<<dim3(NQ / 32, CDIM / 32, BATCH), blkT, 0, stream>>>(q, qf, CDIM, NQ);
  pack_cvt<<<dim3(NKV / 32, CDIM / 32, BATCH), blkT, 0, stream>>>(kv, kvf, CDIM, NKV);

  gemm_bt<0><<<dim3(BATCH * NQ / 128, 512 / 128), blk256, 0, stream>>>(
      qf, wq, bqkv, qhb, BATCH * NQ, 512, 512, 512);
  gemm_bt<0><<<dim3(BATCH * NKV / 128, 1024 / 128), blk256, 0, stream>>>(
      kvf, wq + 512 * 512, bqkv + 512, khv, BATCH * NKV, 1024, 512, 1024);

  transpose_vh<<<dim3(NKV / 32, HD / 32, BATCH * NH), blkT, 0, stream>>>(khv, vt);

  attn_fwd<<<dim3(BATCH * NH, NQ / 64), blk256, 0, stream>>>(qhb, khv, vt, ao);

  // out projection fused with NHWC->NCHW transpose, writes d_out directly
  gemm_bt<2><<<dim3(BATCH * NQ / 128, 512 / 128), blk256, 0, stream>>>(
      ao, wo, bout, out, BATCH * NQ, 512, 512, 512);
}

// Round 12
// 104.360 us; speedup vs baseline: 1.3853x; 1.3853x over previous
//
#include <hip/hip_runtime.h>
#include <hip/hip_bf16.h>
#include <stdint.h>

typedef unsigned short u16;
using bf16x8 = __attribute__((ext_vector_type(8))) short;
using f32x4v = __attribute__((ext_vector_type(4))) float;

#define BATCH 4
#define CDIM 512
#define NQ 1024
#define NKV 2048
#define NH 8
#define HD 64

__device__ __forceinline__ u16 f2bf(float f) {
  uint32_t u = __float_as_uint(f);
  u += 0x7fffu + ((u >> 16) & 1u);
  return (u16)(u >> 16);
}
// compiler-path bf16 cast (pairs fuse to v_cvt_pk_bf16_f32)
__device__ __forceinline__ u16 f2bf_c(float f) {
  __hip_bfloat16 h = __float2bfloat16(f);
  union { __hip_bfloat16 b; u16 u; } cv;
  cv.b = h;
  return cv.u;
}

// ---------------- fp32 -> bf16 convert (weights) ----------------
__global__ void cvt_w(const float* __restrict__ in, u16* __restrict__ out, int n) {
  int i = blockIdx.x * 256 + threadIdx.x;
  if (i < n) out[i] = f2bf(in[i]);
}

// ---------------- (B, C, N) f32 -> (B, N, C) bf16 ----------------
__global__ void pack_cvt(const float* __restrict__ in, u16* __restrict__ out,
                         int C, int N) {
  __shared__ float t[32][33];
  int b = blockIdx.z;
  int n0 = blockIdx.x * 32, c0 = blockIdx.y * 32;
  int tx = threadIdx.x, ty = threadIdx.y;
  const float* ib = in + (size_t)b * C * N;
#pragma unroll
  for (int i = 0; i < 4; ++i)
    t[ty + i * 8][tx] = ib[(size_t)(c0 + ty + i * 8) * N + n0 + tx];
  __syncthreads();
  u16* ob = out + (size_t)b * N * C;
#pragma unroll
  for (int i = 0; i < 4; ++i)
    ob[(size_t)(n0 + ty + i * 8) * C + c0 + tx] = f2bf(t[tx][ty + i * 8]);
}

// ---------------- GEMM: C[m,n] = sum_k A[m,k]*B[n,k] + bias[n] ----------------
// OUTMODE 0: bf16 row-major (ldc). OUTMODE 2: f32 transposed to (B, C, NQ).
// OUTMODE 3 (KV proj): cols<512 (K) -> bf16 kb[row][col], stride 512;
//                      cols>=512 (V) -> bf16 vt[(b*8+h)*64+d][tok] transposed.
template <int OUTMODE>
__global__ __launch_bounds__(256) void gemm_bt(
    const u16* __restrict__ A, const u16* __restrict__ B,
    const float* __restrict__ bias, void* __restrict__ Cout,
    void* __restrict__ Cout2,
    int M, int N, int K, int ldc) {
  __shared__ alignas(16) u16 lsA[2][128 * 32];
  __shared__ alignas(16) u16 lsB[2][128 * 32];
  int t = threadIdx.x, l = t & 63, w = t >> 6;
  int lr = l & 15, lg = l >> 4;
  int wr = w >> 1, wc = w & 1;
  int m0 = blockIdx.x * 128, n0 = blockIdx.y * 128;
  const u16* Ag = A + (size_t)m0 * K;
  const u16* Bg = B + (size_t)n0 * K;
  f32x4v acc[4][4] = {};

  auto stage = [&](int buf, int k0) {
#pragma unroll
    for (int r = 0; r < 2; ++r) {
      int e = (r * 256 + t) * 8;
      int row = e >> 5, col = e & 31;
      __builtin_amdgcn_global_load_lds(
          (const __attribute__((address_space(1))) void*)(Ag + (size_t)row * K + k0 + col),
          (__attribute__((address_space(3))) void*)(&lsA[buf][r * 2048 + w * 512]),
          16, 0, 0);
      __builtin_amdgcn_global_load_lds(
          (const __attribute__((address_space(1))) void*)(Bg + (size_t)row * K + k0 + col),
          (__attribute__((address_space(3))) void*)(&lsB[buf][r * 2048 + w * 512]),
          16, 0, 0);
    }
  };

  stage(0, 0);
  int nk = K >> 5, cur = 0;
  for (int kt = 0; kt < nk; ++kt) {
    __syncthreads();
    if (kt + 1 < nk) stage(cur ^ 1, (kt + 1) << 5);
    const u16* la = lsA[cur];
    const u16* lb = lsB[cur];
    bf16x8 af[4], bfr[4];
#pragma unroll
    for (int m = 0; m < 4; ++m)
      af[m] = *(const bf16x8*)&la[(wr * 64 + m * 16 + lr) * 32 + lg * 8];
#pragma unroll
    for (int n = 0; n < 4; ++n)
      bfr[n] = *(const bf16x8*)&lb[(wc * 64 + n * 16 + lr) * 32 + lg * 8];
#pragma unroll
    for (int m = 0; m < 4; ++m)
#pragma unroll
      for (int n = 0; n < 4; ++n)
        acc[m][n] = __builtin_amdgcn_mfma_f32_16x16x32_bf16(af[m], bfr[n], acc[m][n], 0, 0, 0);
    cur ^= 1;
  }

  // epilogue: C/D layout col=lane&15, row=(lane>>4)*4+j
#pragma unroll
  for (int m = 0; m < 4; ++m) {
    int row = m0 + wr * 64 + m * 16 + lg * 4;
#pragma unroll
    for (int n = 0; n < 4; ++n) {
      int col = n0 + wc * 64 + n * 16 + lr;
      float bv = bias[col];
      if (OUTMODE == 0) {
#pragma unroll
        for (int j = 0; j < 4; ++j)
          ((u16*)Cout)[(size_t)(row + j) * ldc + col] = f2bf(acc[m][n][j] + bv);
      } else if (OUTMODE == 2) {
        // transposed store: token rows row..row+3 -> out[b][col][tok]
        int bb = row >> 10, tok = row & 1023;
        f32x4v v;
#pragma unroll
        for (int j = 0; j < 4; ++j) v[j] = acc[m][n][j] + bv;
        *(f32x4v*)&((float*)Cout)[((size_t)bb * CDIM + col) * NQ + tok] = v;
      } else {  // OUTMODE 3: KV projection
        if (col < 512) {  // K -> kb[row][col], stride 512 (uniform per frag)
#pragma unroll
          for (int j = 0; j < 4; ++j)
            ((u16*)Cout)[(size_t)(row + j) * 512 + col] = f2bf(acc[m][n][j] + bv);
        } else {          // V -> vt[(b*8+h)*64+d][tok], 4 tokens per lane
          int h = (col - 512) >> 6, d = (col - 512) & 63;
          int bb = row >> 11, tok = row & 2047;
          ushort4 v;
          v.x = f2bf_c(acc[m][n][0] + bv); v.y = f2bf_c(acc[m][n][1] + bv);
          v.z = f2bf_c(acc[m][n][2] + bv); v.w = f2bf_c(acc[m][n][3] + bv);
          *(ushort4*)&((u16*)Cout2)[((size_t)(bb * 8 + h) * 64 + d) * NKV + tok] = v;
        }
      }
    }
  }
}

// ---------------- flash attention v7: K triple / V double, counted vmcnt ---
// grid (32 bh, 16 qtiles), block 256 = 4 waves, 16 q-rows/wave, KVBLK=64.
// LDS 48KB -> 3 blocks/CU (12 waves). Issue order per tile: V(t+1), K(t+2);
// steady-state wait vmcnt(2) = {V(t),K(t)} complete, K(t+1) pair may fly.
__global__ __launch_bounds__(256) void attn_fwd(
    const u16* __restrict__ qh,   // (B*NQ, 512)
    const u16* __restrict__ kb,   // (B*NKV, 512) K
    const u16* __restrict__ vt,   // (B*8*64, NKV) V^T
    u16* __restrict__ ao) {       // (B*NQ, 512)
  __shared__ alignas(16) u16 lsK[3][64 * 64];
  __shared__ alignas(16) u16 lsV[2][64 * 64];
  __shared__ alignas(16) u16 plds[4][16 * 64];
  const float scale2 = 0.125f * 1.44269504089f;  // scale * log2(e)
  int t = threadIdx.x, l = t & 63, w = t >> 6;
  int lr = l & 15, lg = l >> 4;
  int bh = blockIdx.x, b = bh >> 3, h = bh & 7;
  int q0 = blockIdx.y * 64 + w * 16;
  const u16* Qb = qh + ((size_t)b * NQ + q0) * 512 + h * HD;
  const u16* Kb = kb + (size_t)b * NKV * 512 + h * HD;
  const u16* Vtb = vt + (size_t)bh * HD * NKV;

  int srow = w * 8 + (l >> 3);   // 0..31: tile row this lane stages
  int c16 = l & 7;               // 16B-block index within 128B row

  auto stageK = [&](int buf, int kv0) {
#pragma unroll
    for (int i = 0; i < 2; ++i) {
      int row = srow + i * 32;
      int sc = c16 ^ (row & 7);  // inverse-swizzled source block
      __builtin_amdgcn_global_load_lds(
          (const __attribute__((address_space(1))) void*)(Kb + (size_t)(kv0 + row) * 512 + sc * 8),
          (__attribute__((address_space(3))) void*)(&lsK[buf][w * 512 + i * 2048]),
          16, 0, 0);
    }
  };
  auto stageV = [&](int buf, int kv0) {
#pragma unroll
    for (int i = 0; i < 2; ++i) {
      int row = srow + i * 32;   // d index
      int sc = c16 ^ (row & 7);
      __builtin_amdgcn_global_load_lds(
          (const __attribute__((address_space(1))) void*)(Vtb + (size_t)row * NKV + kv0 + sc * 8),
          (__attribute__((address_space(3))) void*)(&lsV[buf][w * 512 + i * 2048]),
          16, 0, 0);
    }
  };

  bf16x8 qa[2];
#pragma unroll
  for (int s = 0; s < 2; ++s)
    qa[s] = *(const bf16x8*)(Qb + (size_t)lr * 512 + s * 32 + lg * 8);

  float m2 = -INFINITY;     // running max (log2 domain) for q row = q0+lr
  float lrow = 0.f;         // running denom
  f32x4v od[4] = {};        // O^T: od[n][j] -> d = n*16+lg*4+j, q = lr

  char* pwave = (char*)&plds[w][0];
  int swz = (lr & 7) << 4;

  // prologue issue order: K0, V0, K1  (6 loads/wave)
  stageK(0, 0);
  stageV(0, 0);
  stageK(1, 64);
  const int NT = NKV / 64;
  for (int kt = 0; kt < NT; ++kt) {
    // steady state: allow last-issued K pair to stay in flight
    if (kt < NT - 1) {
      asm volatile("s_waitcnt vmcnt(2)" ::: "memory");
    } else {
      asm volatile("s_waitcnt vmcnt(0)" ::: "memory");
    }
    __builtin_amdgcn_s_barrier();
    __builtin_amdgcn_sched_barrier(0);
    if (kt + 1 < NT) stageV((kt + 1) & 1, (kt + 1) * 64);
    if (kt + 2 < NT) stageK((kt + 2) % 3, (kt + 2) * 64);
    const u16* lk = lsK[kt % 3];
    const u16* lv = lsV[kt & 1];

    // S^T = K Q^T: A = K-frag, B = Q-frag
    f32x4v sfr[4] = {};
    __builtin_amdgcn_s_setprio(1);
#pragma unroll
    for (int sk = 0; sk < 2; ++sk)
#pragma unroll
      for (int n = 0; n < 4; ++n) {
        bf16x8 kbf = *(const bf16x8*)&lk[(n * 16 + lr) * 64 + ((sk * 4 + lg) ^ (lr & 7)) * 8];
        sfr[n] = __builtin_amdgcn_mfma_f32_16x16x32_bf16(kbf, qa[sk], sfr[n], 0, 0, 0);
      }
    __builtin_amdgcn_s_setprio(0);

    // lane-local max over 16 kv values (log2 domain)
    float pm = fmaxf(fmaxf(fmaxf(sfr[0][0], sfr[0][1]), fmaxf(sfr[0][2], sfr[0][3])),
                     fmaxf(fmaxf(sfr[1][0], sfr[1][1]), fmaxf(sfr[1][2], sfr[1][3])));
    float pm2 = fmaxf(fmaxf(fmaxf(sfr[2][0], sfr[2][1]), fmaxf(sfr[2][2], sfr[2][3])),
                      fmaxf(fmaxf(sfr[3][0], sfr[3][1]), fmaxf(sfr[3][2], sfr[3][3])));
    pm = fmaxf(pm, pm2) * scale2;
    pm = fmaxf(pm, __shfl_xor(pm, 16, 64));
    pm = fmaxf(pm, __shfl_xor(pm, 32, 64));

    // exact-skip rescale
    if (__any(pm > m2)) {
      float mn = fmaxf(m2, pm);
      float alpha = __builtin_amdgcn_exp2f(m2 - mn);
      m2 = mn;
      lrow *= alpha;
#pragma unroll
      for (int n = 0; n < 4; ++n)
#pragma unroll
        for (int j = 0; j < 4; ++j)
          od[n][j] *= alpha;
    }

    float p[4][4];
    float rs = 0.f;
#pragma unroll
    for (int n = 0; n < 4; ++n)
#pragma unroll
      for (int j = 0; j < 4; ++j) {
        float e = __builtin_amdgcn_exp2f(fmaf(sfr[n][j], scale2, -m2));
        p[n][j] = e;
        rs += e;
      }
    rs += __shfl_xor(rs, 16, 64);
    rs += __shfl_xor(rs, 32, 64);
    lrow += rs;

    // P[q=lr][kv] -> LDS, 4x ds_write_b64, swizzled (cvt_pk pairs)
#pragma unroll
    for (int n = 0; n < 4; ++n) {
      ushort4 pw;
      pw.x = f2bf_c(p[n][0]); pw.y = f2bf_c(p[n][1]);
      pw.z = f2bf_c(p[n][2]); pw.w = f2bf_c(p[n][3]);
      *(ushort4*)(pwave + lr * 128 + ((n * 32 + lg * 8) ^ swz)) = pw;
    }

    // O^T += V^T P^T: A = V^T-frag, B = P^T from plds
    __builtin_amdgcn_s_setprio(1);
#pragma unroll
    for (int sk = 0; sk < 2; ++sk) {
      bf16x8 pa = *(const bf16x8*)(pwave + lr * 128 + ((sk * 64 + lg * 16) ^ swz));
#pragma unroll
      for (int n = 0; n < 4; ++n) {
        bf16x8 vb = *(const bf16x8*)&lv[(n * 16 + lr) * 64 + ((sk * 4 + lg) ^ (lr & 7)) * 8];
        od[n] = __builtin_amdgcn_mfma_f32_16x16x32_bf16(vb, pa, od[n], 0, 0, 0);
      }
    }
    __builtin_amdgcn_s_setprio(0);
  }

  float rl = 1.0f / lrow;
  u16* aob = ao + ((size_t)b * NQ + q0 + lr) * 512 + h * HD + lg * 4;
#pragma unroll
  for (int n = 0; n < 4; ++n) {
    ushort4 o;
    o.x = f2bf_c(od[n][0] * rl); o.y = f2bf_c(od[n][1] * rl);
    o.z = f2bf_c(od[n][2] * rl); o.w = f2bf_c(od[n][3] * rl);
    *(ushort4*)(aob + n * 16) = o;
  }
}

// ---------------- launch ----------------
extern "C" void kernel_launch(void* const* d_in, const int* in_sizes, int n_in,
                              void* d_out, int out_size, void* d_ws, size_t ws_size,
                              hipStream_t stream) {
  const float* q    = (const float*)d_in[0];
  const float* kv   = (const float*)d_in[1];
  const float* Wqkv = (const float*)d_in[2];
  const float* bqkv = (const float*)d_in[3];
  const float* Wout = (const float*)d_in[4];
  const float* bout = (const float*)d_in[5];
  float* out = (float*)d_out;
  uint8_t* ws = (uint8_t*)d_ws;

  u16* qf  = (u16*)(ws + 0);            // 4 MB  (B*NQ, 512) bf16
  u16* kvf = (u16*)(ws + (4u << 20));   // 8 MB  (B*NKV, 512) bf16
  u16* wq  = (u16*)(ws + (12u << 20));  // 1.5MB Wqkv bf16 (1536,512)
  u16* wo  = (u16*)(ws + (14u << 20));  // 0.5MB Wout bf16 (512,512)
  u16* qhb = (u16*)(ws + (15u << 20));  // 4 MB  (B*NQ, 512)
  u16* kb  = (u16*)(ws + (19u << 20));  // 8 MB  (B*NKV, 512) K
  u16* vt  = (u16*)(ws + (35u << 20));  // 8 MB  (B*8*64, NKV) V^T
  u16* ao  = (u16*)(ws + (43u << 20));  // 4 MB  (B*NQ, 512)

  dim3 blk256(256), blkT(32, 8);

  cvt_w<<<dim3((1536 * 512 + 255) / 256), blk256, 0, stream>>>(Wqkv, wq, 1536 * 512);
  cvt_w<<<dim3((512 * 512 + 255) / 256), blk256, 0, stream>>>(Wout, wo, 512 * 512);
  pack_cvt<<<dim3(NQ / 32, CDIM / 32, BATCH), blkT, 0, stream>>>(q, qf, CDIM, NQ);
  pack_cvt<<<dim3(NKV / 32, CDIM / 32, BATCH), blkT, 0, stream>>>(kv, kvf, CDIM, NKV);

  gemm_bt<0><<<dim3(BATCH * NQ / 128, 512 / 128), blk256, 0, stream>>>(
      qf, wq, bqkv, qhb, nullptr, BATCH * NQ, 512, 512, 512);
  // K,V projection: K -> kb (stride 512), V -> vt transposed (fused)
  gemm_bt<3><<<dim3(BATCH * NKV / 128, 1024 / 128), blk256, 0, stream>>>(
      kvf, wq + 512 * 512, bqkv + 512, kb, vt, BATCH * NKV, 1024, 512, 1024);

  attn_fwd<<<dim3(BATCH * NH, NQ / 64), blk256, 0, stream>>>(qhb, kb, vt, ao);

  // out projection fused with NHWC->NCHW transpose, writes d_out directly
  gemm_bt<2><<<dim3(BATCH * NQ / 128, 512 / 128), blk256, 0, stream>>>(
      ao, wo, bout, out, nullptr, BATCH * NQ, 512, 512, 512);
}

// Round 13
// 88.407 us; speedup vs baseline: 1.6353x; 1.1804x over previous
//
#include <hip/hip_runtime.h>
#include <hip/hip_bf16.h>
#include <stdint.h>

typedef unsigned short u16;
using bf16x8 = __attribute__((ext_vector_type(8))) short;
using f32x4v = __attribute__((ext_vector_type(4))) float;

#define BATCH 4
#define CDIM 512
#define NQ 1024
#define NKV 2048
#define NH 8
#define HD 64

__device__ __forceinline__ u16 f2bf(float f) {
  uint32_t u = __float_as_uint(f);
  u += 0x7fffu + ((u >> 16) & 1u);
  return (u16)(u >> 16);
}
// compiler-path bf16 cast (pairs fuse to v_cvt_pk_bf16_f32)
__device__ __forceinline__ u16 f2bf_c(float f) {
  __hip_bfloat16 h = __float2bfloat16(f);
  union { __hip_bfloat16 b; u16 u; } cv;
  cv.b = h;
  return cv.u;
}

// ---------------- fp32 -> bf16 convert (both weights, one launch) ----------
__global__ void cvt_w2(const float* __restrict__ Wqkv, const float* __restrict__ Wout,
                       u16* __restrict__ wq, u16* __restrict__ wo) {
  int i = blockIdx.x * 256 + threadIdx.x;
  if (i < 1536 * 512) wq[i] = f2bf(Wqkv[i]);
  else wo[i - 1536 * 512] = f2bf(Wout[i - 1536 * 512]);
}

// ---------------- (B, C, N) f32 -> (B, N, C) bf16, q + kv in one launch ----
__global__ void pack_cvt2(const float* __restrict__ q, const float* __restrict__ kv,
                          u16* __restrict__ qf, u16* __restrict__ kvf) {
  __shared__ float tl[32][33];
  int z = blockIdx.z;
  const float* in;
  u16* out;
  int N;
  if (z < BATCH) {
    if (blockIdx.x >= NQ / 32) return;
    in = q + (size_t)z * CDIM * NQ;
    out = qf + (size_t)z * NQ * CDIM;
    N = NQ;
  } else {
    in = kv + (size_t)(z - BATCH) * CDIM * NKV;
    out = kvf + (size_t)(z - BATCH) * NKV * CDIM;
    N = NKV;
  }
  int n0 = blockIdx.x * 32, c0 = blockIdx.y * 32;
  int tx = threadIdx.x, ty = threadIdx.y;
#pragma unroll
  for (int i = 0; i < 4; ++i)
    tl[ty + i * 8][tx] = in[(size_t)(c0 + ty + i * 8) * N + n0 + tx];
  __syncthreads();
#pragma unroll
  for (int i = 0; i < 4; ++i)
    out[(size_t)(n0 + ty + i * 8) * CDIM + c0 + tx] = f2bf(tl[tx][ty + i * 8]);
}

// ---------------- GEMM body: C[m,n] = sum_k A[m,k]*B[n,k] + bias[n] --------
// Triple-buffered LDS, counted vmcnt(4) (one stage = 4 loads/thread in
// flight), raw s_barrier -- no full drain in the K-loop (T4).
// OUTMODE 0: bf16 row-major (ldc). OUTMODE 2: f32 transposed to (B, C, NQ).
// OUTMODE 3 (KV proj): cols<512 K -> kb[row][col] stride 512;
//                      cols>=512 V -> vt[(b*8+h)*64+d][tok] transposed.
template <int OUTMODE>
__device__ __forceinline__ void gemm_body(
    u16 (*lsA)[128 * 32], u16 (*lsB)[128 * 32],
    const u16* __restrict__ A, const u16* __restrict__ Bw,
    const float* __restrict__ bias, void* __restrict__ Cout,
    void* __restrict__ Cout2, int K, int ldc, int bx, int by) {
  int t = threadIdx.x, l = t & 63, w = t >> 6;
  int lr = l & 15, lg = l >> 4;
  int wr = w >> 1, wc = w & 1;
  int m0 = bx * 128, n0 = by * 128;
  const u16* Ag = A + (size_t)m0 * K;
  const u16* Bg = Bw + (size_t)n0 * K;
  f32x4v acc[4][4] = {};

  auto stage = [&](int buf, int k0) {
#pragma unroll
    for (int r = 0; r < 2; ++r) {
      int e = (r * 256 + t) * 8;
      int row = e >> 5, col = e & 31;
      __builtin_amdgcn_global_load_lds(
          (const __attribute__((address_space(1))) void*)(Ag + (size_t)row * K + k0 + col),
          (__attribute__((address_space(3))) void*)(&lsA[buf][r * 2048 + w * 512]),
          16, 0, 0);
      __builtin_amdgcn_global_load_lds(
          (const __attribute__((address_space(1))) void*)(Bg + (size_t)row * K + k0 + col),
          (__attribute__((address_space(3))) void*)(&lsB[buf][r * 2048 + w * 512]),
          16, 0, 0);
    }
  };

  int nk = K >> 5;
  stage(0, 0);
  stage(1, 32);
  for (int kt = 0; kt < nk; ++kt) {
    if (kt < nk - 1) {
      asm volatile("s_waitcnt vmcnt(4)" ::: "memory");   // stage(kt) done
    } else {
      asm volatile("s_waitcnt vmcnt(0)" ::: "memory");
    }
    __builtin_amdgcn_s_barrier();
    __builtin_amdgcn_sched_barrier(0);
    if (kt + 2 < nk) stage((kt + 2) % 3, (kt + 2) << 5);
    const u16* la = lsA[kt % 3];
    const u16* lb = lsB[kt % 3];
    bf16x8 af[4], bfr[4];
#pragma unroll
    for (int m = 0; m < 4; ++m)
      af[m] = *(const bf16x8*)&la[(wr * 64 + m * 16 + lr) * 32 + lg * 8];
#pragma unroll
    for (int n = 0; n < 4; ++n)
      bfr[n] = *(const bf16x8*)&lb[(wc * 64 + n * 16 + lr) * 32 + lg * 8];
    __builtin_amdgcn_s_setprio(1);
#pragma unroll
    for (int m = 0; m < 4; ++m)
#pragma unroll
      for (int n = 0; n < 4; ++n)
        acc[m][n] = __builtin_amdgcn_mfma_f32_16x16x32_bf16(af[m], bfr[n], acc[m][n], 0, 0, 0);
    __builtin_amdgcn_s_setprio(0);
  }

  // epilogue: C/D layout col=lane&15, row=(lane>>4)*4+j
#pragma unroll
  for (int m = 0; m < 4; ++m) {
    int row = m0 + wr * 64 + m * 16 + lg * 4;
#pragma unroll
    for (int n = 0; n < 4; ++n) {
      int col = n0 + wc * 64 + n * 16 + lr;
      float bv = bias[col];
      if (OUTMODE == 0) {
#pragma unroll
        for (int j = 0; j < 4; ++j)
          ((u16*)Cout)[(size_t)(row + j) * ldc + col] = f2bf(acc[m][n][j] + bv);
      } else if (OUTMODE == 2) {
        // transposed store: token rows row..row+3 -> out[b][col][tok]
        int bb = row >> 10, tok = row & 1023;
        f32x4v v;
#pragma unroll
        for (int j = 0; j < 4; ++j) v[j] = acc[m][n][j] + bv;
        *(f32x4v*)&((float*)Cout)[((size_t)bb * CDIM + col) * NQ + tok] = v;
      } else {  // OUTMODE 3: KV projection
        if (col < 512) {  // K -> kb[row][col], stride 512
#pragma unroll
          for (int j = 0; j < 4; ++j)
            ((u16*)Cout)[(size_t)(row + j) * 512 + col] = f2bf(acc[m][n][j] + bv);
        } else {          // V -> vt[(b*8+h)*64+d][tok], 4 tokens per lane
          int h = (col - 512) >> 6, d = (col - 512) & 63;
          int bb = row >> 11, tok = row & 2047;
          ushort4 v;
          v.x = f2bf_c(acc[m][n][0] + bv); v.y = f2bf_c(acc[m][n][1] + bv);
          v.z = f2bf_c(acc[m][n][2] + bv); v.w = f2bf_c(acc[m][n][3] + bv);
          *(ushort4*)&((u16*)Cout2)[((size_t)(bb * 8 + h) * 64 + d) * NKV + tok] = v;
        }
      }
    }
  }
}

// ---------------- fused Q-proj + KV-proj (one dispatch) --------------------
// grid (64, 8, 2): z=0 -> Q projection (active 32x4 blocks), z=1 -> KV.
__global__ __launch_bounds__(256) void qkv_proj(
    const u16* __restrict__ qf, const u16* __restrict__ kvf,
    const u16* __restrict__ wq, const float* __restrict__ bqkv,
    u16* __restrict__ qhb, u16* __restrict__ kb, u16* __restrict__ vt) {
  __shared__ alignas(16) u16 lsA[3][128 * 32];
  __shared__ alignas(16) u16 lsB[3][128 * 32];
  if (blockIdx.z == 0) {
    if (blockIdx.x >= 32 || blockIdx.y >= 4) return;
    gemm_body<0>(lsA, lsB, qf, wq, bqkv, qhb, nullptr, 512, 512,
                 blockIdx.x, blockIdx.y);
  } else {
    gemm_body<3>(lsA, lsB, kvf, wq + 512 * 512, bqkv + 512, kb, vt, 512, 1024,
                 blockIdx.x, blockIdx.y);
  }
}

// ---------------- out projection (fused NHWC->NCHW transpose) --------------
__global__ __launch_bounds__(256) void out_proj(
    const u16* __restrict__ ao, const u16* __restrict__ wo,
    const float* __restrict__ bout, float* __restrict__ out) {
  __shared__ alignas(16) u16 lsA[3][128 * 32];
  __shared__ alignas(16) u16 lsB[3][128 * 32];
  gemm_body<2>(lsA, lsB, ao, wo, bout, out, nullptr, 512, 512,
               blockIdx.x, blockIdx.y);
}

// ---------------- flash attention v7: K triple / V double, counted vmcnt ---
// grid (32 bh, 16 qtiles), block 256 = 4 waves, 16 q-rows/wave, KVBLK=64.
// Issue order per tile: V(t+1), K(t+2); steady-state wait vmcnt(2).
__global__ __launch_bounds__(256) void attn_fwd(
    const u16* __restrict__ qh,   // (B*NQ, 512)
    const u16* __restrict__ kb,   // (B*NKV, 512) K
    const u16* __restrict__ vt,   // (B*8*64, NKV) V^T
    u16* __restrict__ ao) {       // (B*NQ, 512)
  __shared__ alignas(16) u16 lsK[3][64 * 64];
  __shared__ alignas(16) u16 lsV[2][64 * 64];
  __shared__ alignas(16) u16 plds[4][16 * 64];
  const float scale2 = 0.125f * 1.44269504089f;  // scale * log2(e)
  int t = threadIdx.x, l = t & 63, w = t >> 6;
  int lr = l & 15, lg = l >> 4;
  int bh = blockIdx.x, b = bh >> 3, h = bh & 7;
  int q0 = blockIdx.y * 64 + w * 16;
  const u16* Qb = qh + ((size_t)b * NQ + q0) * 512 + h * HD;
  const u16* Kb = kb + (size_t)b * NKV * 512 + h * HD;
  const u16* Vtb = vt + (size_t)bh * HD * NKV;

  int srow = w * 8 + (l >> 3);   // 0..31: tile row this lane stages
  int c16 = l & 7;               // 16B-block index within 128B row

  auto stageK = [&](int buf, int kv0) {
#pragma unroll
    for (int i = 0; i < 2; ++i) {
      int row = srow + i * 32;
      int sc = c16 ^ (row & 7);  // inverse-swizzled source block
      __builtin_amdgcn_global_load_lds(
          (const __attribute__((address_space(1))) void*)(Kb + (size_t)(kv0 + row) * 512 + sc * 8),
          (__attribute__((address_space(3))) void*)(&lsK[buf][w * 512 + i * 2048]),
          16, 0, 0);
    }
  };
  auto stageV = [&](int buf, int kv0) {
#pragma unroll
    for (int i = 0; i < 2; ++i) {
      int row = srow + i * 32;   // d index
      int sc = c16 ^ (row & 7);
      __builtin_amdgcn_global_load_lds(
          (const __attribute__((address_space(1))) void*)(Vtb + (size_t)row * NKV + kv0 + sc * 8),
          (__attribute__((address_space(3))) void*)(&lsV[buf][w * 512 + i * 2048]),
          16, 0, 0);
    }
  };

  bf16x8 qa[2];
#pragma unroll
  for (int s = 0; s < 2; ++s)
    qa[s] = *(const bf16x8*)(Qb + (size_t)lr * 512 + s * 32 + lg * 8);

  float m2 = -INFINITY;     // running max (log2 domain) for q row = q0+lr
  float lrow = 0.f;         // running denom
  f32x4v od[4] = {};        // O^T: od[n][j] -> d = n*16+lg*4+j, q = lr

  char* pwave = (char*)&plds[w][0];
  int swz = (lr & 7) << 4;

  // prologue issue order: K0, V0, K1  (6 loads/wave)
  stageK(0, 0);
  stageV(0, 0);
  stageK(1, 64);
  const int NT = NKV / 64;
  for (int kt = 0; kt < NT; ++kt) {
    // steady state: allow last-issued K pair to stay in flight
    if (kt < NT - 1) {
      asm volatile("s_waitcnt vmcnt(2)" ::: "memory");
    } else {
      asm volatile("s_waitcnt vmcnt(0)" ::: "memory");
    }
    __builtin_amdgcn_s_barrier();
    __builtin_amdgcn_sched_barrier(0);
    if (kt + 1 < NT) stageV((kt + 1) & 1, (kt + 1) * 64);
    if (kt + 2 < NT) stageK((kt + 2) % 3, (kt + 2) * 64);
    const u16* lk = lsK[kt % 3];
    const u16* lv = lsV[kt & 1];

    // S^T = K Q^T: A = K-frag, B = Q-frag
    f32x4v sfr[4] = {};
    __builtin_amdgcn_s_setprio(1);
#pragma unroll
    for (int sk = 0; sk < 2; ++sk)
#pragma unroll
      for (int n = 0; n < 4; ++n) {
        bf16x8 kbf = *(const bf16x8*)&lk[(n * 16 + lr) * 64 + ((sk * 4 + lg) ^ (lr & 7)) * 8];
        sfr[n] = __builtin_amdgcn_mfma_f32_16x16x32_bf16(kbf, qa[sk], sfr[n], 0, 0, 0);
      }
    __builtin_amdgcn_s_setprio(0);

    // lane-local max over 16 kv values (log2 domain)
    float pm = fmaxf(fmaxf(fmaxf(sfr[0][0], sfr[0][1]), fmaxf(sfr[0][2], sfr[0][3])),
                     fmaxf(fmaxf(sfr[1][0], sfr[1][1]), fmaxf(sfr[1][2], sfr[1][3])));
    float pm2 = fmaxf(fmaxf(fmaxf(sfr[2][0], sfr[2][1]), fmaxf(sfr[2][2], sfr[2][3])),
                      fmaxf(fmaxf(sfr[3][0], sfr[3][1]), fmaxf(sfr[3][2], sfr[3][3])));
    pm = fmaxf(pm, pm2) * scale2;
    pm = fmaxf(pm, __shfl_xor(pm, 16, 64));
    pm = fmaxf(pm, __shfl_xor(pm, 32, 64));

    // exact-skip rescale
    if (__any(pm > m2)) {
      float mn = fmaxf(m2, pm);
      float alpha = __builtin_amdgcn_exp2f(m2 - mn);
      m2 = mn;
      lrow *= alpha;
#pragma unroll
      for (int n = 0; n < 4; ++n)
#pragma unroll
        for (int j = 0; j < 4; ++j)
          od[n][j] *= alpha;
    }

    float p[4][4];
    float rs = 0.f;
#pragma unroll
    for (int n = 0; n < 4; ++n)
#pragma unroll
      for (int j = 0; j < 4; ++j) {
        float e = __builtin_amdgcn_exp2f(fmaf(sfr[n][j], scale2, -m2));
        p[n][j] = e;
        rs += e;
      }
    rs += __shfl_xor(rs, 16, 64);
    rs += __shfl_xor(rs, 32, 64);
    lrow += rs;

    // P[q=lr][kv] -> LDS, 4x ds_write_b64, swizzled (cvt_pk pairs)
#pragma unroll
    for (int n = 0; n < 4; ++n) {
      ushort4 pw;
      pw.x = f2bf_c(p[n][0]); pw.y = f2bf_c(p[n][1]);
      pw.z = f2bf_c(p[n][2]); pw.w = f2bf_c(p[n][3]);
      *(ushort4*)(pwave + lr * 128 + ((n * 32 + lg * 8) ^ swz)) = pw;
    }

    // O^T += V^T P^T: A = V^T-frag, B = P^T from plds
    __builtin_amdgcn_s_setprio(1);
#pragma unroll
    for (int sk = 0; sk < 2; ++sk) {
      bf16x8 pa = *(const bf16x8*)(pwave + lr * 128 + ((sk * 64 + lg * 16) ^ swz));
#pragma unroll
      for (int n = 0; n < 4; ++n) {
        bf16x8 vb = *(const bf16x8*)&lv[(n * 16 + lr) * 64 + ((sk * 4 + lg) ^ (lr & 7)) * 8];
        od[n] = __builtin_amdgcn_mfma_f32_16x16x32_bf16(vb, pa, od[n], 0, 0, 0);
      }
    }
    __builtin_amdgcn_s_setprio(0);
  }

  float rl = 1.0f / lrow;
  u16* aob = ao + ((size_t)b * NQ + q0 + lr) * 512 + h * HD + lg * 4;
#pragma unroll
  for (int n = 0; n < 4; ++n) {
    ushort4 o;
    o.x = f2bf_c(od[n][0] * rl); o.y = f2bf_c(od[n][1] * rl);
    o.z = f2bf_c(od[n][2] * rl); o.w = f2bf_c(od[n][3] * rl);
    *(ushort4*)(aob + n * 16) = o;
  }
}

// ---------------- launch ----------------
extern "C" void kernel_launch(void* const* d_in, const int* in_sizes, int n_in,
                              void* d_out, int out_size, void* d_ws, size_t ws_size,
                              hipStream_t stream) {
  const float* q    = (const float*)d_in[0];
  const float* kv   = (const float*)d_in[1];
  const float* Wqkv = (const float*)d_in[2];
  const float* bqkv = (const float*)d_in[3];
  const float* Wout = (const float*)d_in[4];
  const float* bout = (const float*)d_in[5];
  float* out = (float*)d_out;
  uint8_t* ws = (uint8_t*)d_ws;

  u16* qf  = (u16*)(ws + 0);            // 4 MB  (B*NQ, 512) bf16
  u16* kvf = (u16*)(ws + (4u << 20));   // 8 MB  (B*NKV, 512) bf16
  u16* wq  = (u16*)(ws + (12u << 20));  // 1.5MB Wqkv bf16 (1536,512)
  u16* wo  = (u16*)(ws + (14u << 20));  // 0.5MB Wout bf16 (512,512)
  u16* qhb = (u16*)(ws + (15u << 20));  // 4 MB  (B*NQ, 512)
  u16* kb  = (u16*)(ws + (19u << 20));  // 8 MB  (B*NKV, 512) K
  u16* vt  = (u16*)(ws + (35u << 20));  // 8 MB  (B*8*64, NKV) V^T
  u16* ao  = (u16*)(ws + (43u << 20));  // 4 MB  (B*NQ, 512)

  dim3 blk256(256), blkT(32, 8);

  cvt_w2<<<dim3((2048 * 512 + 255) / 256), blk256, 0, stream>>>(Wqkv, Wout, wq, wo);
  pack_cvt2<<<dim3(NKV / 32, CDIM / 32, 2 * BATCH), blkT, 0, stream>>>(q, kv, qf, kvf);

  // Q-proj (z=0) + KV-proj (z=1) in one dispatch
  qkv_proj<<<dim3(BATCH * NKV / 128, 1024 / 128, 2), blk256, 0, stream>>>(
      qf, kvf, wq, bqkv, qhb, kb, vt);

  attn_fwd<<<dim3(BATCH * NH, NQ / 64), blk256, 0, stream>>>(qhb, kb, vt, ao);

  // out projection fused with NHWC->NCHW transpose, writes d_out directly
  out_proj<<<dim3(BATCH * NQ / 128, 512 / 128), blk256, 0, stream>>>(
      ao, wo, bout, out);
}

// Round 14
// 85.812 us; speedup vs baseline: 1.6847x; 1.0302x over previous
//
#include <hip/hip_runtime.h>
#include <hip/hip_bf16.h>
#include <stdint.h>

typedef unsigned short u16;
using bf16x8 = __attribute__((ext_vector_type(8))) short;
using f32x4v = __attribute__((ext_vector_type(4))) float;

#define BATCH 4
#define CDIM 512
#define NQ 1024
#define NKV 2048
#define NH 8
#define HD 64

__device__ __forceinline__ u16 f2bf(float f) {
  uint32_t u = __float_as_uint(f);
  u += 0x7fffu + ((u >> 16) & 1u);
  return (u16)(u >> 16);
}
// compiler-path bf16 cast (pairs fuse to v_cvt_pk_bf16_f32)
__device__ __forceinline__ u16 f2bf_c(float f) {
  __hip_bfloat16 h = __float2bfloat16(f);
  union { __hip_bfloat16 b; u16 u; } cv;
  cv.b = h;
  return cv.u;
}

// ---------------- fp32 -> bf16 convert (both weights, one launch) ----------
__global__ void cvt_w2(const float* __restrict__ Wqkv, const float* __restrict__ Wout,
                       u16* __restrict__ wq, u16* __restrict__ wo) {
  int i = blockIdx.x * 256 + threadIdx.x;
  if (i < 1536 * 512) wq[i] = f2bf(Wqkv[i]);
  else wo[i - 1536 * 512] = f2bf(Wout[i - 1536 * 512]);
}

// ---------------- (B, C, N) f32 -> (B, N, C) bf16, q + kv in one launch ----
// 64-channel x 32-token tiles; stores paired bf16 as u32 (128B/wave rows).
__global__ void pack_cvt2(const float* __restrict__ q, const float* __restrict__ kv,
                          u16* __restrict__ qf, u16* __restrict__ kvf) {
  __shared__ float tl[64][33];
  int z = blockIdx.z;
  const float* in;
  u16* out;
  int N;
  if (z < BATCH) {
    if (blockIdx.x >= NQ / 32) return;
    in = q + (size_t)z * CDIM * NQ;
    out = qf + (size_t)z * NQ * CDIM;
    N = NQ;
  } else {
    in = kv + (size_t)(z - BATCH) * CDIM * NKV;
    out = kvf + (size_t)(z - BATCH) * NKV * CDIM;
    N = NKV;
  }
  int n0 = blockIdx.x * 32, c0 = blockIdx.y * 64;
  int tx = threadIdx.x, ty = threadIdx.y;
#pragma unroll
  for (int i = 0; i < 8; ++i)
    tl[ty + i * 8][tx] = in[(size_t)(c0 + ty + i * 8) * N + n0 + tx];
  __syncthreads();
#pragma unroll
  for (int i = 0; i < 4; ++i) {
    int tloc = ty + i * 8;
    uint32_t lo = f2bf(tl[2 * tx][tloc]);
    uint32_t hi = f2bf(tl[2 * tx + 1][tloc]);
    *(uint32_t*)&out[(size_t)(n0 + tloc) * CDIM + c0 + 2 * tx] = lo | (hi << 16);
  }
}

// ---------------- GEMM body: C[m,n] = sum_k A[m,k]*B[n,k] + bias[n] --------
// Triple-buffered LDS, counted vmcnt(4), raw s_barrier (T4).
// OUTMODE 0: bf16 row-major (ldc). OUTMODE 2: f32 transposed to (B, C, NQ).
// OUTMODE 3 (KV proj): cols<512 K -> kb[row][col] stride 512;
//                      cols>=512 V -> vt[(b*8+h)*64+d][tok] transposed.
template <int OUTMODE>
__device__ __forceinline__ void gemm_body(
    u16 (*lsA)[128 * 32], u16 (*lsB)[128 * 32],
    const u16* __restrict__ A, const u16* __restrict__ Bw,
    const float* __restrict__ bias, void* __restrict__ Cout,
    void* __restrict__ Cout2, int K, int ldc, int bx, int by) {
  int t = threadIdx.x, l = t & 63, w = t >> 6;
  int lr = l & 15, lg = l >> 4;
  int wr = w >> 1, wc = w & 1;
  int m0 = bx * 128, n0 = by * 128;
  const u16* Ag = A + (size_t)m0 * K;
  const u16* Bg = Bw + (size_t)n0 * K;
  f32x4v acc[4][4] = {};

  auto stage = [&](int buf, int k0) {
#pragma unroll
    for (int r = 0; r < 2; ++r) {
      int e = (r * 256 + t) * 8;
      int row = e >> 5, col = e & 31;
      __builtin_amdgcn_global_load_lds(
          (const __attribute__((address_space(1))) void*)(Ag + (size_t)row * K + k0 + col),
          (__attribute__((address_space(3))) void*)(&lsA[buf][r * 2048 + w * 512]),
          16, 0, 0);
      __builtin_amdgcn_global_load_lds(
          (const __attribute__((address_space(1))) void*)(Bg + (size_t)row * K + k0 + col),
          (__attribute__((address_space(3))) void*)(&lsB[buf][r * 2048 + w * 512]),
          16, 0, 0);
    }
  };

  int nk = K >> 5;
  stage(0, 0);
  stage(1, 32);
  for (int kt = 0; kt < nk; ++kt) {
    if (kt < nk - 1) {
      asm volatile("s_waitcnt vmcnt(4)" ::: "memory");   // stage(kt) done
    } else {
      asm volatile("s_waitcnt vmcnt(0)" ::: "memory");
    }
    __builtin_amdgcn_s_barrier();
    __builtin_amdgcn_sched_barrier(0);
    if (kt + 2 < nk) stage((kt + 2) % 3, (kt + 2) << 5);
    const u16* la = lsA[kt % 3];
    const u16* lb = lsB[kt % 3];
    bf16x8 af[4], bfr[4];
#pragma unroll
    for (int m = 0; m < 4; ++m)
      af[m] = *(const bf16x8*)&la[(wr * 64 + m * 16 + lr) * 32 + lg * 8];
#pragma unroll
    for (int n = 0; n < 4; ++n)
      bfr[n] = *(const bf16x8*)&lb[(wc * 64 + n * 16 + lr) * 32 + lg * 8];
    __builtin_amdgcn_s_setprio(1);
#pragma unroll
    for (int m = 0; m < 4; ++m)
#pragma unroll
      for (int n = 0; n < 4; ++n)
        acc[m][n] = __builtin_amdgcn_mfma_f32_16x16x32_bf16(af[m], bfr[n], acc[m][n], 0, 0, 0);
    __builtin_amdgcn_s_setprio(0);
  }

  // epilogue: C/D layout col=lane&15, row=(lane>>4)*4+j
#pragma unroll
  for (int m = 0; m < 4; ++m) {
    int row = m0 + wr * 64 + m * 16 + lg * 4;
#pragma unroll
    for (int n = 0; n < 4; ++n) {
      int col = n0 + wc * 64 + n * 16 + lr;
      float bv = bias[col];
      if (OUTMODE == 0) {
#pragma unroll
        for (int j = 0; j < 4; ++j)
          ((u16*)Cout)[(size_t)(row + j) * ldc + col] = f2bf(acc[m][n][j] + bv);
      } else if (OUTMODE == 2) {
        // transposed store: token rows row..row+3 -> out[b][col][tok]
        int bb = row >> 10, tok = row & 1023;
        f32x4v v;
#pragma unroll
        for (int j = 0; j < 4; ++j) v[j] = acc[m][n][j] + bv;
        *(f32x4v*)&((float*)Cout)[((size_t)bb * CDIM + col) * NQ + tok] = v;
      } else {  // OUTMODE 3: KV projection
        if (col < 512) {  // K -> kb[row][col], stride 512
#pragma unroll
          for (int j = 0; j < 4; ++j)
            ((u16*)Cout)[(size_t)(row + j) * 512 + col] = f2bf(acc[m][n][j] + bv);
        } else {          // V -> vt[(b*8+h)*64+d][tok], 4 tokens per lane
          int h = (col - 512) >> 6, d = (col - 512) & 63;
          int bb = row >> 11, tok = row & 2047;
          ushort4 v;
          v.x = f2bf_c(acc[m][n][0] + bv); v.y = f2bf_c(acc[m][n][1] + bv);
          v.z = f2bf_c(acc[m][n][2] + bv); v.w = f2bf_c(acc[m][n][3] + bv);
          *(ushort4*)&((u16*)Cout2)[((size_t)(bb * 8 + h) * 64 + d) * NKV + tok] = v;
        }
      }
    }
  }
}

// ---------------- fused Q-proj + KV-proj (one dispatch) --------------------
__global__ __launch_bounds__(256) void qkv_proj(
    const u16* __restrict__ qf, const u16* __restrict__ kvf,
    const u16* __restrict__ wq, const float* __restrict__ bqkv,
    u16* __restrict__ qhb, u16* __restrict__ kb, u16* __restrict__ vt) {
  __shared__ alignas(16) u16 lsA[3][128 * 32];
  __shared__ alignas(16) u16 lsB[3][128 * 32];
  if (blockIdx.z == 0) {
    if (blockIdx.x >= 32 || blockIdx.y >= 4) return;
    gemm_body<0>(lsA, lsB, qf, wq, bqkv, qhb, nullptr, 512, 512,
                 blockIdx.x, blockIdx.y);
  } else {
    gemm_body<3>(lsA, lsB, kvf, wq + 512 * 512, bqkv + 512, kb, vt, 512, 1024,
                 blockIdx.x, blockIdx.y);
  }
}

// ---------------- out projection (fused NHWC->NCHW transpose) --------------
__global__ __launch_bounds__(256) void out_proj(
    const u16* __restrict__ ao, const u16* __restrict__ wo,
    const float* __restrict__ bout, float* __restrict__ out) {
  __shared__ alignas(16) u16 lsA[3][128 * 32];
  __shared__ alignas(16) u16 lsB[3][128 * 32];
  gemm_body<2>(lsA, lsB, ao, wo, bout, out, nullptr, 512, 512,
               blockIdx.x, blockIdx.y);
}

// ---------------- flash attention v8: deferred row-sum + threshold skip ----
// grid (32 bh, 16 qtiles), block 256 = 4 waves, 16 q-rows/wave, KVBLK=64.
// K triple-buffered / V double-buffered, counted vmcnt(2).
// lrow kept as PER-LANE partial (alpha is wave-row-uniform) -> the 2 sum
// shfls per tile move to the epilogue. Rescale skipped unless pm > m2+8
// (P bounded by 2^8, fine in f32 accum).
__global__ __launch_bounds__(256) void attn_fwd(
    const u16* __restrict__ qh,   // (B*NQ, 512)
    const u16* __restrict__ kb,   // (B*NKV, 512) K
    const u16* __restrict__ vt,   // (B*8*64, NKV) V^T
    u16* __restrict__ ao) {       // (B*NQ, 512)
  __shared__ alignas(16) u16 lsK[3][64 * 64];
  __shared__ alignas(16) u16 lsV[2][64 * 64];
  __shared__ alignas(16) u16 plds[4][16 * 64];
  const float scale2 = 0.125f * 1.44269504089f;  // scale * log2(e)
  int t = threadIdx.x, l = t & 63, w = t >> 6;
  int lr = l & 15, lg = l >> 4;
  int bh = blockIdx.x, b = bh >> 3, h = bh & 7;
  int q0 = blockIdx.y * 64 + w * 16;
  const u16* Qb = qh + ((size_t)b * NQ + q0) * 512 + h * HD;
  const u16* Kb = kb + (size_t)b * NKV * 512 + h * HD;
  const u16* Vtb = vt + (size_t)bh * HD * NKV;

  int srow = w * 8 + (l >> 3);   // 0..31: tile row this lane stages
  int c16 = l & 7;               // 16B-block index within 128B row

  auto stageK = [&](int buf, int kv0) {
#pragma unroll
    for (int i = 0; i < 2; ++i) {
      int row = srow + i * 32;
      int sc = c16 ^ (row & 7);  // inverse-swizzled source block
      __builtin_amdgcn_global_load_lds(
          (const __attribute__((address_space(1))) void*)(Kb + (size_t)(kv0 + row) * 512 + sc * 8),
          (__attribute__((address_space(3))) void*)(&lsK[buf][w * 512 + i * 2048]),
          16, 0, 0);
    }
  };
  auto stageV = [&](int buf, int kv0) {
#pragma unroll
    for (int i = 0; i < 2; ++i) {
      int row = srow + i * 32;   // d index
      int sc = c16 ^ (row & 7);
      __builtin_amdgcn_global_load_lds(
          (const __attribute__((address_space(1))) void*)(Vtb + (size_t)row * NKV + kv0 + sc * 8),
          (__attribute__((address_space(3))) void*)(&lsV[buf][w * 512 + i * 2048]),
          16, 0, 0);
    }
  };

  bf16x8 qa[2];
#pragma unroll
  for (int s = 0; s < 2; ++s)
    qa[s] = *(const bf16x8*)(Qb + (size_t)lr * 512 + s * 32 + lg * 8);

  float m2 = -INFINITY;     // running max (log2 domain), uniform per q-row
  float lrow = 0.f;         // PER-LANE partial denom (reduced in epilogue)
  f32x4v od[4] = {};        // O^T: od[n][j] -> d = n*16+lg*4+j, q = lr

  char* pwave = (char*)&plds[w][0];
  int swz = (lr & 7) << 4;

  // prologue issue order: K0, V0, K1  (6 loads/wave)
  stageK(0, 0);
  stageV(0, 0);
  stageK(1, 64);
  const int NT = NKV / 64;
  for (int kt = 0; kt < NT; ++kt) {
    // steady state: allow last-issued K pair to stay in flight
    if (kt < NT - 1) {
      asm volatile("s_waitcnt vmcnt(2)" ::: "memory");
    } else {
      asm volatile("s_waitcnt vmcnt(0)" ::: "memory");
    }
    __builtin_amdgcn_s_barrier();
    __builtin_amdgcn_sched_barrier(0);
    if (kt + 1 < NT) stageV((kt + 1) & 1, (kt + 1) * 64);
    if (kt + 2 < NT) stageK((kt + 2) % 3, (kt + 2) * 64);
    const u16* lk = lsK[kt % 3];
    const u16* lv = lsV[kt & 1];

    // S^T = K Q^T: A = K-frag, B = Q-frag
    f32x4v sfr[4] = {};
    __builtin_amdgcn_s_setprio(1);
#pragma unroll
    for (int sk = 0; sk < 2; ++sk)
#pragma unroll
      for (int n = 0; n < 4; ++n) {
        bf16x8 kbf = *(const bf16x8*)&lk[(n * 16 + lr) * 64 + ((sk * 4 + lg) ^ (lr & 7)) * 8];
        sfr[n] = __builtin_amdgcn_mfma_f32_16x16x32_bf16(kbf, qa[sk], sfr[n], 0, 0, 0);
      }
    __builtin_amdgcn_s_setprio(0);

    // lane-local max over 16 kv values (log2 domain)
    float pm = fmaxf(fmaxf(fmaxf(sfr[0][0], sfr[0][1]), fmaxf(sfr[0][2], sfr[0][3])),
                     fmaxf(fmaxf(sfr[1][0], sfr[1][1]), fmaxf(sfr[1][2], sfr[1][3])));
    float pm2 = fmaxf(fmaxf(fmaxf(sfr[2][0], sfr[2][1]), fmaxf(sfr[2][2], sfr[2][3])),
                      fmaxf(fmaxf(sfr[3][0], sfr[3][1]), fmaxf(sfr[3][2], sfr[3][3])));
    pm = fmaxf(pm, pm2) * scale2;
    pm = fmaxf(pm, __shfl_xor(pm, 16, 64));
    pm = fmaxf(pm, __shfl_xor(pm, 32, 64));

    // threshold-skip rescale (T13): P bounded by 2^8 when skipped
    if (__any(pm > m2 + 8.f)) {
      float mn = fmaxf(m2, pm);
      float alpha = __builtin_amdgcn_exp2f(m2 - mn);
      m2 = mn;
      lrow *= alpha;
#pragma unroll
      for (int n = 0; n < 4; ++n)
#pragma unroll
        for (int j = 0; j < 4; ++j)
          od[n][j] *= alpha;
    }

    float p[4][4];
#pragma unroll
    for (int n = 0; n < 4; ++n)
#pragma unroll
      for (int j = 0; j < 4; ++j) {
        float e = __builtin_amdgcn_exp2f(fmaf(sfr[n][j], scale2, -m2));
        p[n][j] = e;
        lrow += e;            // per-lane partial; reduced once at the end
      }

    // P[q=lr][kv] -> LDS, 4x ds_write_b64, swizzled (cvt_pk pairs)
#pragma unroll
    for (int n = 0; n < 4; ++n) {
      ushort4 pw;
      pw.x = f2bf_c(p[n][0]); pw.y = f2bf_c(p[n][1]);
      pw.z = f2bf_c(p[n][2]); pw.w = f2bf_c(p[n][3]);
      *(ushort4*)(pwave + lr * 128 + ((n * 32 + lg * 8) ^ swz)) = pw;
    }

    // O^T += V^T P^T: A = V^T-frag, B = P^T from plds
    __builtin_amdgcn_s_setprio(1);
#pragma unroll
    for (int sk = 0; sk < 2; ++sk) {
      bf16x8 pa = *(const bf16x8*)(pwave + lr * 128 + ((sk * 64 + lg * 16) ^ swz));
#pragma unroll
      for (int n = 0; n < 4; ++n) {
        bf16x8 vb = *(const bf16x8*)&lv[(n * 16 + lr) * 64 + ((sk * 4 + lg) ^ (lr & 7)) * 8];
        od[n] = __builtin_amdgcn_mfma_f32_16x16x32_bf16(vb, pa, od[n], 0, 0, 0);
      }
    }
    __builtin_amdgcn_s_setprio(0);
  }

  // epilogue: reduce per-lane partial lrow across the q-row's 4 lanes
  lrow += __shfl_xor(lrow, 16, 64);
  lrow += __shfl_xor(lrow, 32, 64);
  float rl = 1.0f / lrow;
  u16* aob = ao + ((size_t)b * NQ + q0 + lr) * 512 + h * HD + lg * 4;
#pragma unroll
  for (int n = 0; n < 4; ++n) {
    ushort4 o;
    o.x = f2bf_c(od[n][0] * rl); o.y = f2bf_c(od[n][1] * rl);
    o.z = f2bf_c(od[n][2] * rl); o.w = f2bf_c(od[n][3] * rl);
    *(ushort4*)(aob + n * 16) = o;
  }
}

// ---------------- launch ----------------
extern "C" void kernel_launch(void* const* d_in, const int* in_sizes, int n_in,
                              void* d_out, int out_size, void* d_ws, size_t ws_size,
                              hipStream_t stream) {
  const float* q    = (const float*)d_in[0];
  const float* kv   = (const float*)d_in[1];
  const float* Wqkv = (const float*)d_in[2];
  const float* bqkv = (const float*)d_in[3];
  const float* Wout = (const float*)d_in[4];
  const float* bout = (const float*)d_in[5];
  float* out = (float*)d_out;
  uint8_t* ws = (uint8_t*)d_ws;

  u16* qf  = (u16*)(ws + 0);            // 4 MB  (B*NQ, 512) bf16
  u16* kvf = (u16*)(ws + (4u << 20));   // 8 MB  (B*NKV, 512) bf16
  u16* wq  = (u16*)(ws + (12u << 20));  // 1.5MB Wqkv bf16 (1536,512)
  u16* wo  = (u16*)(ws + (14u << 20));  // 0.5MB Wout bf16 (512,512)
  u16* qhb = (u16*)(ws + (15u << 20));  // 4 MB  (B*NQ, 512)
  u16* kb  = (u16*)(ws + (19u << 20));  // 8 MB  (B*NKV, 512) K
  u16* vt  = (u16*)(ws + (35u << 20));  // 8 MB  (B*8*64, NKV) V^T
  u16* ao  = (u16*)(ws + (43u << 20));  // 4 MB  (B*NQ, 512)

  dim3 blk256(256), blkT(32, 8);

  cvt_w2<<<dim3((2048 * 512 + 255) / 256), blk256, 0, stream>>>(Wqkv, Wout, wq, wo);
  pack_cvt2<<<dim3(NKV / 32, CDIM / 64, 2 * BATCH), blkT, 0, stream>>>(q, kv, qf, kvf);

  // Q-proj (z=0) + KV-proj (z=1) in one dispatch
  qkv_proj<<<dim3(BATCH * NKV / 128, 1024 / 128, 2), blk256, 0, stream>>>(
      qf, kvf, wq, bqkv, qhb, kb, vt);

  attn_fwd<<<dim3(BATCH * NH, NQ / 64), blk256, 0, stream>>>(qhb, kb, vt, ao);

  // out projection fused with NHWC->NCHW transpose, writes d_out directly
  out_proj<<<dim3(BATCH * NQ / 128, 512 / 128), blk256, 0, stream>>>(
      ao, wo, bout, out);
}